// Round 5
// baseline (630.191 us; speedup 1.0000x reference)
//
#include <hip/hip_runtime.h>
#include <math.h>

#define LNB      32
#define NODE_IN  128
#define EDGE_IN  64
#define TIME_D   128
#define D_MODEL  320
#define N_HEAD   8
#define D_K      64
#define NHD      512
#define HID      128
#define IN2      448
#define N_DSTN   8192

typedef __attribute__((ext_vector_type(8))) short bf16x8;
typedef __attribute__((ext_vector_type(4))) float f32x4;
#define MFMA16(a,b,c) __builtin_amdgcn_mfma_f32_16x16x32_bf16(a,b,c,0,0,0)

// ---- ws layout (elements of unsigned short) ----
#define WS_QKM   0            // 8192*2560 : qk -> mbar (in place)
#define WS_WQK   20971520     // 2560*128  : folded wk@wq
#define WS_WVF   21299200     // 320*2560  : folded fcw@wv
#define WS_NWC   22118400     // 128*448   : [nw1 | nw2*lng]
#define WS_F32   22175744     // float region (3520 floats)
// float region offsets (in floats)
#define F_C0     0            // 512
#define F_C0K    512          // 2560
#define F_CC     3072         // 320  : fcb + q-const residual
#define F_B2     3392         // 128  : nb + nw2@lnb
// total ws = 44,365,568 bytes

__device__ __forceinline__ unsigned short f2bf(float f) {
  union { float f; unsigned i; } v; v.f = f;
  unsigned x = v.i;
  return (unsigned short)((x + 0x7fffu + ((x >> 16) & 1u)) >> 16); // RTNE
}
__device__ __forceinline__ float2 bf2f2(unsigned u) {
  union { unsigned i; float f; } lo, hi;
  lo.i = u << 16; hi.i = u & 0xffff0000u;
  return make_float2(lo.f, hi.f);
}
__device__ __forceinline__ void up8(uint4 v, float* o) {
  float2 a = bf2f2(v.x), b = bf2f2(v.y), c = bf2f2(v.z), d = bf2f2(v.w);
  o[0]=a.x; o[1]=a.y; o[2]=b.x; o[3]=b.y; o[4]=c.x; o[5]=c.y; o[6]=d.x; o[7]=d.y;
}
__device__ __forceinline__ bf16x8 pack8(const float* v) {
  unsigned short b8[8];
  #pragma unroll
  for (int j = 0; j < 8; ++j) b8[j] = f2bf(v[j]);
  return *(const bf16x8*)b8;
}

// =================== prep1: nw fold + constants ============================
__global__ __launch_bounds__(256)
void prep1(const float* __restrict__ wq, const float* __restrict__ lng,
           const float* __restrict__ lnb_, const float* __restrict__ nw,
           const float* __restrict__ nb, const float* __restrict__ fcb,
           const float* __restrict__ ph, unsigned short* __restrict__ ws)
{
  int i = blockIdx.x * 256 + threadIdx.x;
  unsigned short* nwc = ws + WS_NWC;
  float* f32r = (float*)(ws + WS_F32);
  if (i < 16384) {                       // nw1 cast
    int o = i >> 7, k = i & 127;
    nwc[o * IN2 + k] = f2bf(nw[(size_t)o * IN2 + k]);
  } else if (i < 57344) {                // nw2g = nw2 * lng
    int j = i - 16384, o = j / 320, c = j - o * 320;
    nwc[o * IN2 + 128 + c] = f2bf(nw[(size_t)o * IN2 + 128 + c] * lng[c]);
  } else if (i < 57856) {                // c0[j] = cos(ph) . wq[j][192:]
    int j = i - 57344;
    float s = 0.f;
    for (int k = 0; k < 128; ++k) s += __cosf(ph[k]) * wq[(size_t)j * D_MODEL + 192 + k];
    f32r[F_C0 + j] = s;
  } else if (i < 58176) {                // cc[c] = fcb + q-const
    int c = i - 57856;
    f32r[F_CC + c] = fcb[c] + (c >= 192 ? __cosf(ph[c - 192]) : 0.f);
  } else if (i < 58304) {                // bias2[o] = nb + nw2 . lnb
    int o = i - 58176;
    float s = nb[o];
    for (int c = 0; c < 320; ++c) s += nw[(size_t)o * IN2 + 128 + c] * lnb_[c];
    f32r[F_B2 + o] = s;
  }
}

// =================== prep2: wqk, c0k, wvf ==================================
__global__ __launch_bounds__(256)
void prep2(const float* __restrict__ wq, const float* __restrict__ wk,
           const float* __restrict__ wv, const float* __restrict__ fcw,
           unsigned short* __restrict__ ws)
{
  int i = blockIdx.x * 256 + threadIdx.x;
  float* f32r = (float*)(ws + WS_F32);
  if (i < 327680) {                      // wqk[hd][k] = sum_dk wq[h64+dk][k]*wk[h64+dk][d]
    int hd = i >> 7, k = i & 127;
    int h = hd / 320, d = hd - h * 320;
    const float* wqb = wq + (size_t)h * 64 * D_MODEL + k;
    const float* wkb = wk + (size_t)h * 64 * D_MODEL + d;
    float s = 0.f;
    for (int dk = 0; dk < 64; ++dk) s += wqb[(size_t)dk * D_MODEL] * wkb[(size_t)dk * D_MODEL];
    ws[WS_WQK + (size_t)hd * 128 + k] = f2bf(s);
  } else if (i < 330240) {               // c0k[hd] = c0[h64+dk] . wk[.][d]
    int hd = i - 327680;
    int h = hd / 320, d = hd - h * 320;
    float s = 0.f;
    for (int dk = 0; dk < 64; ++dk)
      s += f32r[F_C0 + h * 64 + dk] * wk[(size_t)(h * 64 + dk) * D_MODEL + d];
    f32r[F_C0K + hd] = s;
  } else if (i < 1149440) {              // wvf[c][hd] = sum_jj fcw[c][h64+jj]*wv[h64+jj][d]
    int j = i - 330240;
    int c = j / 2560, hd = j - c * 2560;
    int h = hd / 320, d = hd - h * 320;
    const float* fb  = fcw + (size_t)c * NHD + h * 64;
    const float* wvb = wv + (size_t)h * 64 * D_MODEL + d;
    float s = 0.f;
    for (int jj = 0; jj < 64; ++jj) s += fb[jj] * wvb[(size_t)jj * D_MODEL];
    ws[WS_WVF + (size_t)c * 2560 + hd] = f2bf(s);
  }
}

// =================== K1: qk = nf @ wqk^T + c0k  (M=8192,N=2560,K=128) ======
// Mtile 64 x Ntile 128, grid 128*20, 256 thr. LDS 17.4 KB.
__global__ __launch_bounds__(256, 6)
void tgat_qk(const float* __restrict__ nf, const unsigned short* __restrict__ ws,
             unsigned short* __restrict__ qkm)
{
  __shared__ alignas(16) unsigned short sA[64 * 136];
  const int tid = threadIdx.x, wid = tid >> 6, lane = tid & 63, qd = lane >> 4, lm = lane & 15;
  const int mt_blk = blockIdx.x / 20, nt_blk = blockIdx.x - mt_blk * 20;
  const int n0 = mt_blk * 64, c0 = nt_blk * 128;
  const unsigned short* wqk = ws + WS_WQK;
  const float* f32r = (const float*)(ws + WS_F32);

  { // stage A: 64 x 128 bf16 (coalesced)
    int n = tid >> 2, k0 = (tid & 3) * 32;
    const float4* src = (const float4*)(nf + (size_t)(n0 + n) * NODE_IN + k0);
    #pragma unroll
    for (int q = 0; q < 4; ++q) {
      float4 f0 = src[2 * q], f1 = src[2 * q + 1];
      float v[8] = {f0.x, f0.y, f0.z, f0.w, f1.x, f1.y, f1.z, f1.w};
      *(bf16x8*)&sA[n * 136 + k0 + q * 8] = pack8(v);
    }
  }
  __syncthreads();

  // wave w: nt {2w,2w+1}, all 4 mt
  f32x4 acc[2][4] = {};
  for (int kt = 0; kt < 4; ++kt) {
    bf16x8 a[4];
    #pragma unroll
    for (int mt = 0; mt < 4; ++mt)
      a[mt] = *(const bf16x8*)&sA[(mt * 16 + lm) * 136 + kt * 32 + qd * 8];
    #pragma unroll
    for (int t = 0; t < 2; ++t) {
      int cg = c0 + (2 * wid + t) * 16 + lm;
      bf16x8 b = *(const bf16x8*)&wqk[(size_t)cg * 128 + kt * 32 + qd * 8];
      #pragma unroll
      for (int mt = 0; mt < 4; ++mt) acc[t][mt] = MFMA16(a[mt], b, acc[t][mt]);
    }
  }
  #pragma unroll
  for (int t = 0; t < 2; ++t) {
    int cg = c0 + (2 * wid + t) * 16 + lm;
    float ck = f32r[F_C0K + cg];
    #pragma unroll
    for (int mt = 0; mt < 4; ++mt)
      #pragma unroll
      for (int r = 0; r < 4; ++r)
        qkm[(size_t)(n0 + mt * 16 + qd * 4 + r) * 2560 + cg] = f2bf(acc[t][mt][r] + ck);
  }
}

// =================== K2: attention (1 node / 256-thr block) ================
// LDS ~23 KB -> 5-6 blocks/CU.
__global__ __launch_bounds__(256, 5)
void tgat_attn(const float* __restrict__ nf, const float* __restrict__ ef,
               const float* __restrict__ dtp, const int* __restrict__ nidx,
               const float* __restrict__ freq, const float* __restrict__ ph,
               unsigned short* __restrict__ qkm)
{
  __shared__ alignas(16) unsigned short sM[LNB * 328];   // 20.5 KB
  __shared__ float sATTf[8 * 36];                        // 1.2 KB
  __shared__ float sFP[TIME_D], sPH[TIME_D], sDT[LNB];
  __shared__ int sNI[16];

  const int tid = threadIdx.x, wid = tid >> 6, lane = tid & 63, qd = lane >> 4, lm = lane & 15;
  const int n = blockIdx.x;
  unsigned short* qn = qkm + (size_t)n * 2560;

  if (tid < TIME_D) { sFP[tid] = freq[tid]; sPH[tid] = ph[tid]; }
  if (tid < 16) sNI[tid] = nidx[n * 16 + tid];
  if (tid < LNB) sDT[tid] = dtp[(size_t)n * LNB + tid];

  // wave0: prefetch qk B-frags into regs (overlaps m-build)
  bf16x8 qkB[10];
  if (wid == 0) {
    #pragma unroll
    for (int kt = 0; kt < 10; ++kt) {
      bf16x8 z = {0,0,0,0,0,0,0,0};
      qkB[kt] = z;
      if (lm < 8) qkB[kt] = *(const bf16x8*)&qn[lm * 320 + kt * 32 + qd * 8];
    }
  }
  __syncthreads();

  // m build (row-major only); per-iteration branch is wave-uniform
  #pragma unroll
  for (int it = 0; it < 5; ++it) {
    int g = it * 256 + tid;
    int l = g & 31, dg = g >> 5, d0 = dg * 8;
    float v[8];
    if (dg < 16) {
      const float4* src = (const float4*)(nf + (size_t)sNI[l >> 1] * NODE_IN + d0);
      float4 f0 = src[0], f1 = src[1];
      v[0]=f0.x; v[1]=f0.y; v[2]=f0.z; v[3]=f0.w; v[4]=f1.x; v[5]=f1.y; v[6]=f1.z; v[7]=f1.w;
    } else if (dg < 24) {
      const float4* src = (const float4*)(ef + ((size_t)n * LNB + l) * EDGE_IN + (d0 - NODE_IN));
      float4 f0 = src[0], f1 = src[1];
      v[0]=f0.x; v[1]=f0.y; v[2]=f0.z; v[3]=f0.w; v[4]=f1.x; v[5]=f1.y; v[6]=f1.z; v[7]=f1.w;
    } else {
      int dd = d0 - 192;
      float dt = sDT[l];
      #pragma unroll
      for (int j = 0; j < 8; ++j) v[j] = __cosf(dt * sFP[dd + j] + sPH[dd + j]);
    }
    *(bf16x8*)&sM[l * 328 + d0] = pack8(v);
  }
  __syncthreads();

  // scores + softmax (wave 0 only)
  if (wid == 0) {
    f32x4 acc0 = {}, acc1 = {};
    for (int kt = 0; kt < 10; ++kt) {
      bf16x8 a0 = *(const bf16x8*)&sM[lm * 328 + kt * 32 + qd * 8];
      bf16x8 a1 = *(const bf16x8*)&sM[(16 + lm) * 328 + kt * 32 + qd * 8];
      acc0 = MFMA16(a0, qkB[kt], acc0);
      acc1 = MFMA16(a1, qkB[kt], acc1);
    }
    float s[8], e[8];
    #pragma unroll
    for (int r = 0; r < 4; ++r) { s[r] = acc0[r] * 0.125f; s[4 + r] = acc1[r] * 0.125f; }
    float mx = s[0];
    #pragma unroll
    for (int i = 1; i < 8; ++i) mx = fmaxf(mx, s[i]);
    mx = fmaxf(mx, __shfl_xor(mx, 16));
    mx = fmaxf(mx, __shfl_xor(mx, 32));
    float sum = 0.f;
    #pragma unroll
    for (int i = 0; i < 8; ++i) { e[i] = __expf(s[i] - mx); sum += e[i]; }
    sum += __shfl_xor(sum, 16);
    sum += __shfl_xor(sum, 32);
    float inv = 1.f / sum;
    #pragma unroll
    for (int i = 0; i < 8; ++i) {
      int l = (i < 4) ? (qd * 4 + i) : (16 + qd * 4 + (i - 4));
      if (lm < 8) sATTf[lm * 36 + l] = e[i] * inv;
    }
  }
  __syncthreads();

  // mbar[h][d] = att @ m via VALU -> overwrite qkm[n]
  for (int item = tid; item < 320; item += 256) {
    int h = item / 40, c = item - h * 40;
    const float* att = &sATTf[h * 36];
    float a[8] = {};
    int rot = tid & 31;
    for (int ll = 0; ll < LNB; ++ll) {
      int l = (ll + rot) & 31;                    // rotate to spread LDS banks
      float at = att[l];
      float mv[8]; up8(*(const uint4*)&sM[l * 328 + c * 8], mv);
      #pragma unroll
      for (int j = 0; j < 8; ++j) a[j] += at * mv[j];
    }
    *(bf16x8*)&qn[h * 320 + c * 8] = pack8(a);
  }
}

// =================== K3: x = mbar@wvf^T (+cc+res) -> LN -> out =============
// Mtile 32, 512 thr (8 waves), grid 256. LDS ~31 KB.
__global__ __launch_bounds__(512, 2)
void tgat_post(const float* __restrict__ nf, const unsigned short* __restrict__ ws,
               const unsigned short* __restrict__ qkm, float* __restrict__ out)
{
  __shared__ alignas(16) unsigned short sQb[32 * 136];   // 8.7 KB h_dst bf16
  __shared__ alignas(16) unsigned short sXb[32 * 328];   // 21 KB xhat bf16
  __shared__ float sRed[8][4][4][2];                     // 1 KB
  __shared__ float sStat[32][2];

  const int tid = threadIdx.x, wid = tid >> 6, lane = tid & 63, qd = lane >> 4, lm = lane & 15;
  const int n0 = blockIdx.x * 32;
  const int mt = wid & 1, ws4 = wid >> 1;                // wave -> mtile, nt-set
  const unsigned short* wvf = ws + WS_WVF;
  const unsigned short* nwc = ws + WS_NWC;
  const float* f32r = (const float*)(ws + WS_F32);

  { // stage h_dst bf16 (coalesced)
    int nn = tid >> 4, k0 = (tid & 15) * 8;
    const float4* src = (const float4*)(nf + (size_t)(n0 + nn) * NODE_IN + k0);
    float4 f0 = src[0], f1 = src[1];
    float v[8] = {f0.x, f0.y, f0.z, f0.w, f1.x, f1.y, f1.z, f1.w};
    *(bf16x8*)&sQb[nn * 136 + k0] = pack8(v);
  }

  // x GEMM: K=2560; wave: 5 N-tiles (nt = ws4 + 4u) for its mtile
  f32x4 acc[5] = {};
  const unsigned short* arow = qkm + (size_t)(n0 + mt * 16 + lm) * 2560;
  for (int kt = 0; kt < 80; ++kt) {
    bf16x8 a = *(const bf16x8*)&arow[kt * 32 + qd * 8];
    #pragma unroll
    for (int u = 0; u < 5; ++u) {
      int c = (ws4 + 4 * u) * 16 + lm;
      bf16x8 b = *(const bf16x8*)&wvf[(size_t)c * 2560 + kt * 32 + qd * 8];
      acc[u] = MFMA16(a, b, acc[u]);
    }
  }

  // epilogue: + cc + residual; LN stats in-register
  float val[5][4];
  float s1[4] = {}, s2[4] = {};
  #pragma unroll
  for (int u = 0; u < 5; ++u) {
    int t = ws4 + 4 * u, c = t * 16 + lm;
    float ccv = f32r[F_CC + c];
    #pragma unroll
    for (int r = 0; r < 4; ++r) {
      float v = acc[u][r] + ccv;
      if (t < 8) v += nf[(size_t)(n0 + mt * 16 + qd * 4 + r) * NODE_IN + c];
      val[u][r] = v;
      s1[r] += v; s2[r] += v * v;
    }
  }
  #pragma unroll
  for (int off = 1; off <= 8; off <<= 1) {
    #pragma unroll
    for (int r = 0; r < 4; ++r) {
      s1[r] += __shfl_xor(s1[r], off);
      s2[r] += __shfl_xor(s2[r], off);
    }
  }
  if (lm == 0) {
    #pragma unroll
    for (int r = 0; r < 4; ++r) { sRed[wid][qd][r][0] = s1[r]; sRed[wid][qd][r][1] = s2[r]; }
  }
  __syncthreads();
  if (tid < 32) {
    int m2 = tid >> 4, rr = tid & 15, q = rr >> 2, r = rr & 3;
    float S = 0.f, S2 = 0.f;
    #pragma unroll
    for (int j = 0; j < 4; ++j) { S += sRed[2 * j + m2][q][r][0]; S2 += sRed[2 * j + m2][q][r][1]; }
    float mean = S * (1.f / D_MODEL);
    float var = S2 * (1.f / D_MODEL) - mean * mean;
    sStat[tid][0] = mean;
    sStat[tid][1] = rsqrtf(var + 1e-5f);
  }
  __syncthreads();
  #pragma unroll
  for (int u = 0; u < 5; ++u) {
    int c = (ws4 + 4 * u) * 16 + lm;
    #pragma unroll
    for (int r = 0; r < 4; ++r) {
      int row = mt * 16 + qd * 4 + r;
      float xh = (val[u][r] - sStat[row][0]) * sStat[row][1];
      sXb[row * 328 + c] = f2bf(xh);
    }
  }
  __syncthreads();

  // out GEMM: M=32, N=128, K=448; wave w -> N-tile w, both mtiles
  f32x4 oacc[2] = {};
  for (int kt = 0; kt < 14; ++kt) {
    bf16x8 a[2];
    #pragma unroll
    for (int m2 = 0; m2 < 2; ++m2) {
      if (kt < 4) a[m2] = *(const bf16x8*)&sQb[(m2 * 16 + lm) * 136 + kt * 32 + qd * 8];
      else        a[m2] = *(const bf16x8*)&sXb[(m2 * 16 + lm) * 328 + (kt - 4) * 32 + qd * 8];
    }
    int o = wid * 16 + lm;
    bf16x8 b = *(const bf16x8*)&nwc[(size_t)o * IN2 + kt * 32 + qd * 8];
    oacc[0] = MFMA16(a[0], b, oacc[0]);
    oacc[1] = MFMA16(a[1], b, oacc[1]);
  }
  {
    int o = wid * 16 + lm;
    float bz = f32r[F_B2 + o];
    #pragma unroll
    for (int m2 = 0; m2 < 2; ++m2)
      #pragma unroll
      for (int r = 0; r < 4; ++r)
        out[(size_t)(n0 + m2 * 16 + qd * 4 + r) * HID + o] = fmaxf(oacc[m2][r] + bz, 0.f);
  }
}

extern "C" void kernel_launch(void* const* d_in, const int* in_sizes, int n_in,
                              void* d_out, int out_size, void* d_ws, size_t ws_size,
                              hipStream_t stream) {
  const float* nf   = (const float*)d_in[0];
  const float* ef   = (const float*)d_in[1];
  const float* dtp  = (const float*)d_in[2];
  const int*   nidx = (const int*)  d_in[3];
  const float* freq = (const float*)d_in[4];
  const float* ph   = (const float*)d_in[5];
  const float* wq   = (const float*)d_in[6];
  const float* wk   = (const float*)d_in[7];
  const float* wv   = (const float*)d_in[8];
  const float* fcw  = (const float*)d_in[9];
  const float* fcb  = (const float*)d_in[10];
  const float* lng  = (const float*)d_in[11];
  const float* lnb_ = (const float*)d_in[12];
  const float* nw   = (const float*)d_in[13];
  const float* nb   = (const float*)d_in[14];
  float* out = (float*)d_out;
  unsigned short* ws = (unsigned short*)d_ws;
  unsigned short* qkm = ws + WS_QKM;

  prep1<<<228, 256, 0, stream>>>(wq, lng, lnb_, nw, nb, fcb, ph, ws);
  prep2<<<4490, 256, 0, stream>>>(wq, wk, wv, fcw, ws);
  tgat_qk  <<<2560, 256, 0, stream>>>(nf, ws, qkm);
  tgat_attn<<<8192, 256, 0, stream>>>(nf, ef, dtp, nidx, freq, ph, qkm);
  tgat_post<<<256,  512, 0, stream>>>(nf, ws, qkm, out);
}

// Round 6
// 384.143 us; speedup vs baseline: 1.6405x; 1.6405x over previous
//
#include <hip/hip_runtime.h>
#include <math.h>

#define LNB      32
#define NODE_IN  128
#define EDGE_IN  64
#define TIME_D   128
#define D_MODEL  320
#define N_HEAD   8
#define D_K      64
#define NHD      512
#define HID      128
#define IN2      448
#define N_DSTN   8192

typedef __attribute__((ext_vector_type(8))) short bf16x8;
typedef __attribute__((ext_vector_type(4))) float f32x4;
#define MFMA16(a,b,c) __builtin_amdgcn_mfma_f32_16x16x32_bf16(a,b,c,0,0,0)

// ---- ws layout (elements of unsigned short) ----
#define WS_QKM   0            // 8192*2560 : qk -> mbar (in place)
#define WS_WQK   20971520     // 2560*128  : folded wk@wq
#define WS_WVF   21299200     // 320*2560  : folded fcw@wv
#define WS_NWC   22118400     // 128*448   : [nw1 | nw2*lng]
#define WS_F32   22175744     // float region (3520 floats)
#define F_C0     0            // 512
#define F_C0K    512          // 2560
#define F_CC     3072         // 320  : fcb + q-const residual
#define F_B2     3392         // 128  : nb + nw2@lnb

__device__ __forceinline__ unsigned short f2bf(float f) {
  union { float f; unsigned i; } v; v.f = f;
  unsigned x = v.i;
  return (unsigned short)((x + 0x7fffu + ((x >> 16) & 1u)) >> 16); // RTNE
}
__device__ __forceinline__ bf16x8 pack8(const float* v) {
  unsigned short b8[8];
  #pragma unroll
  for (int j = 0; j < 8; ++j) b8[j] = f2bf(v[j]);
  return *(const bf16x8*)b8;
}

// =================== prep1: nw fold + constants ============================
__global__ __launch_bounds__(256)
void prep1(const float* __restrict__ wq, const float* __restrict__ lng,
           const float* __restrict__ lnb_, const float* __restrict__ nw,
           const float* __restrict__ nb, const float* __restrict__ fcb,
           const float* __restrict__ ph, unsigned short* __restrict__ ws)
{
  int i = blockIdx.x * 256 + threadIdx.x;
  unsigned short* nwc = ws + WS_NWC;
  float* f32r = (float*)(ws + WS_F32);
  if (i < 16384) {                       // nw1 cast
    int o = i >> 7, k = i & 127;
    nwc[o * IN2 + k] = f2bf(nw[(size_t)o * IN2 + k]);
  } else if (i < 57344) {                // nw2g = nw2 * lng
    int j = i - 16384, o = j / 320, c = j - o * 320;
    nwc[o * IN2 + 128 + c] = f2bf(nw[(size_t)o * IN2 + 128 + c] * lng[c]);
  } else if (i < 57856) {                // c0[j] = cos(ph) . wq[j][192:]
    int j = i - 57344;
    float s = 0.f;
    for (int k = 0; k < 128; ++k) s += __cosf(ph[k]) * wq[(size_t)j * D_MODEL + 192 + k];
    f32r[F_C0 + j] = s;
  } else if (i < 58176) {                // cc[c] = fcb + q-const
    int c = i - 57856;
    f32r[F_CC + c] = fcb[c] + (c >= 192 ? __cosf(ph[c - 192]) : 0.f);
  } else if (i < 58304) {                // bias2[o] = nb + nw2 . lnb
    int o = i - 58176;
    float s = nb[o];
    for (int c = 0; c < 320; ++c) s += nw[(size_t)o * IN2 + 128 + c] * lnb_[c];
    f32r[F_B2 + o] = s;
  }
}

// =================== prep2: wqk, c0k, wvf ==================================
__global__ __launch_bounds__(256)
void prep2(const float* __restrict__ wq, const float* __restrict__ wk,
           const float* __restrict__ wv, const float* __restrict__ fcw,
           unsigned short* __restrict__ ws)
{
  int i = blockIdx.x * 256 + threadIdx.x;
  float* f32r = (float*)(ws + WS_F32);
  if (i < 327680) {                      // wqk[hd][k] = sum_dk wq[h64+dk][k]*wk[h64+dk][d]
    int hd = i >> 7, k = i & 127;
    int h = hd / 320, d = hd - h * 320;
    const float* wqb = wq + (size_t)h * 64 * D_MODEL + k;
    const float* wkb = wk + (size_t)h * 64 * D_MODEL + d;
    float s = 0.f;
    for (int dk = 0; dk < 64; ++dk) s += wqb[(size_t)dk * D_MODEL] * wkb[(size_t)dk * D_MODEL];
    ws[WS_WQK + (size_t)hd * 128 + k] = f2bf(s);
  } else if (i < 330240) {               // c0k[hd] = c0[h64+dk] . wk[.][d]
    int hd = i - 327680;
    int h = hd / 320, d = hd - h * 320;
    float s = 0.f;
    for (int dk = 0; dk < 64; ++dk)
      s += f32r[F_C0 + h * 64 + dk] * wk[(size_t)(h * 64 + dk) * D_MODEL + d];
    f32r[F_C0K + hd] = s;
  } else if (i < 1149440) {              // wvf[c][hd] = sum_jj fcw[c][h64+jj]*wv[h64+jj][d]
    int j = i - 330240;
    int c = j / 2560, hd = j - c * 2560;
    int h = hd / 320, d = hd - h * 320;
    const float* fb  = fcw + (size_t)c * NHD + h * 64;
    const float* wvb = wv + (size_t)h * 64 * D_MODEL + d;
    float s = 0.f;
    for (int jj = 0; jj < 64; ++jj) s += fb[jj] * wvb[(size_t)jj * D_MODEL];
    ws[WS_WVF + (size_t)c * 2560 + hd] = f2bf(s);
  }
}

// =================== K1: qk = nf @ wqk^T + c0k  (M=8192,N=2560,K=128) ======
__global__ __launch_bounds__(256, 6)
void tgat_qk(const float* __restrict__ nf, const unsigned short* __restrict__ ws,
             unsigned short* __restrict__ qkm)
{
  __shared__ alignas(16) unsigned short sA[64 * 136];
  const int tid = threadIdx.x, wid = tid >> 6, lane = tid & 63, qd = lane >> 4, lm = lane & 15;
  const int mt_blk = blockIdx.x / 20, nt_blk = blockIdx.x - mt_blk * 20;
  const int n0 = mt_blk * 64, c0 = nt_blk * 128;
  const unsigned short* wqk = ws + WS_WQK;
  const float* f32r = (const float*)(ws + WS_F32);

  { // stage A: 64 x 128 bf16 (coalesced)
    int n = tid >> 2, k0 = (tid & 3) * 32;
    const float4* src = (const float4*)(nf + (size_t)(n0 + n) * NODE_IN + k0);
    #pragma unroll
    for (int q = 0; q < 4; ++q) {
      float4 f0 = src[2 * q], f1 = src[2 * q + 1];
      float v[8] = {f0.x, f0.y, f0.z, f0.w, f1.x, f1.y, f1.z, f1.w};
      *(bf16x8*)&sA[n * 136 + k0 + q * 8] = pack8(v);
    }
  }
  __syncthreads();

  f32x4 acc[2][4] = {};
  for (int kt = 0; kt < 4; ++kt) {
    bf16x8 a[4];
    #pragma unroll
    for (int mt = 0; mt < 4; ++mt)
      a[mt] = *(const bf16x8*)&sA[(mt * 16 + lm) * 136 + kt * 32 + qd * 8];
    #pragma unroll
    for (int t = 0; t < 2; ++t) {
      int cg = c0 + (2 * wid + t) * 16 + lm;
      bf16x8 b = *(const bf16x8*)&wqk[(size_t)cg * 128 + kt * 32 + qd * 8];
      #pragma unroll
      for (int mt = 0; mt < 4; ++mt) acc[t][mt] = MFMA16(a[mt], b, acc[t][mt]);
    }
  }
  #pragma unroll
  for (int t = 0; t < 2; ++t) {
    int cg = c0 + (2 * wid + t) * 16 + lm;
    float ck = f32r[F_C0K + cg];
    #pragma unroll
    for (int mt = 0; mt < 4; ++mt)
      #pragma unroll
      for (int r = 0; r < 4; ++r)
        qkm[(size_t)(n0 + mt * 16 + qd * 4 + r) * 2560 + cg] = f2bf(acc[t][mt][r] + ck);
  }
}

// =================== K2: attention (R4-proven structure) ====================
// 1 node / 256-thr block; LDS ~49 KB -> 3 blocks/CU; no cross-barrier reg prefetch.
__global__ __launch_bounds__(256, 3)
void tgat_attn(const float* __restrict__ nf, const float* __restrict__ ef,
               const float* __restrict__ dtp, const int* __restrict__ nidx,
               const float* __restrict__ freq, const float* __restrict__ ph,
               unsigned short* __restrict__ qkm)
{
  __shared__ alignas(16) unsigned short sM [LNB * 328];    // 20.5 KB row-major
  __shared__ alignas(16) unsigned short sMT[D_MODEL * 40]; // 25.6 KB col-major
  __shared__ alignas(16) unsigned short sATT[16 * 40];     // 1.28 KB
  __shared__ float sFP[TIME_D], sPH[TIME_D], sDT[LNB];
  __shared__ int   sNI[16];

  const int tid = threadIdx.x;
  const int wid = tid >> 6, lane = tid & 63, qd = lane >> 4, lm = lane & 15;
  const int n = blockIdx.x;

  if (tid < TIME_D) { sFP[tid] = freq[tid]; sPH[tid] = ph[tid]; }
  if (tid < 16)  sNI[tid] = nidx[n * 16 + tid];
  if (tid < LNB) sDT[tid] = dtp[(size_t)n * LNB + tid];
  __syncthreads();

  // m build: thread -> (l = g&31, d-group g>>5 of 8 consecutive d)
  #pragma unroll 1
  for (int it = 0; it < 5; ++it) {
    int g = it * 256 + tid;
    int l = g & 31, dg = g >> 5;
    int d0 = dg * 8;
    float v[8];
    if (dg < 16) {
      const float4* src = (const float4*)(nf + (size_t)sNI[l >> 1] * NODE_IN + d0);
      float4 f0 = src[0], f1 = src[1];
      v[0]=f0.x; v[1]=f0.y; v[2]=f0.z; v[3]=f0.w; v[4]=f1.x; v[5]=f1.y; v[6]=f1.z; v[7]=f1.w;
    } else if (dg < 24) {
      const float4* src = (const float4*)(ef + ((size_t)n * LNB + l) * EDGE_IN + (d0 - NODE_IN));
      float4 f0 = src[0], f1 = src[1];
      v[0]=f0.x; v[1]=f0.y; v[2]=f0.z; v[3]=f0.w; v[4]=f1.x; v[5]=f1.y; v[6]=f1.z; v[7]=f1.w;
    } else {
      int dd = d0 - 192;
      float dt = sDT[l];
      #pragma unroll
      for (int j = 0; j < 8; ++j) v[j] = __cosf(dt * sFP[dd + j] + sPH[dd + j]);
    }
    unsigned short b8[8];
    #pragma unroll
    for (int j = 0; j < 8; ++j) b8[j] = f2bf(v[j]);
    *(bf16x8*)&sM[l * 328 + d0] = *(const bf16x8*)b8;
    #pragma unroll
    for (int j = 0; j < 8; ++j) sMT[(d0 + j) * 40 + l] = b8[j];
  }
  __syncthreads();

  // scores + softmax (wave 0): D[l][h] = m @ qk^T / 8
  if (wid == 0) {
    const unsigned short* qn = qkm + (size_t)n * 2560;
    f32x4 acc0 = {}, acc1 = {};
    for (int kt = 0; kt < 10; ++kt) {
      bf16x8 b = {0,0,0,0,0,0,0,0};
      if (lm < 8) b = *(const bf16x8*)&qn[lm * D_MODEL + kt * 32 + qd * 8];
      bf16x8 a0 = *(const bf16x8*)&sM[lm * 328 + kt * 32 + qd * 8];
      bf16x8 a1 = *(const bf16x8*)&sM[(16 + lm) * 328 + kt * 32 + qd * 8];
      acc0 = MFMA16(a0, b, acc0);
      acc1 = MFMA16(a1, b, acc1);
    }
    float s[8], e[8];
    #pragma unroll
    for (int r = 0; r < 4; ++r) { s[r] = acc0[r] * 0.125f; s[4 + r] = acc1[r] * 0.125f; }
    float mx = s[0];
    #pragma unroll
    for (int i = 1; i < 8; ++i) mx = fmaxf(mx, s[i]);
    mx = fmaxf(mx, __shfl_xor(mx, 16));
    mx = fmaxf(mx, __shfl_xor(mx, 32));
    float sum = 0.f;
    #pragma unroll
    for (int i = 0; i < 8; ++i) { e[i] = __expf(s[i] - mx); sum += e[i]; }
    sum += __shfl_xor(sum, 16);
    sum += __shfl_xor(sum, 32);
    float inv = 1.f / sum;
    #pragma unroll
    for (int i = 0; i < 8; ++i) {
      int l = (i < 4) ? (qd * 4 + i) : (16 + qd * 4 + (i - 4));
      sATT[lm * 40 + l] = f2bf(e[i] * inv);
    }
  }
  __syncthreads();

  // mbar[h][d] = attn @ m  (MFMA, K=32) -> overwrite qkm[n]
  {
    bf16x8 a = *(const bf16x8*)&sATT[lm * 40 + qd * 8];
    for (int dt = wid; dt < 20; dt += 4) {
      int d = dt * 16 + lm;
      bf16x8 b = *(const bf16x8*)&sMT[d * 40 + qd * 8];
      f32x4 acc = {};
      acc = MFMA16(a, b, acc);
      if (qd < 2) {
        #pragma unroll
        for (int r = 0; r < 4; ++r)
          qkm[(size_t)n * 2560 + (qd * 4 + r) * D_MODEL + d] = f2bf(acc[r]);
      }
    }
  }
}

// =================== K3: x = mbar@wvf^T (+cc+res) -> LN -> out =============
__global__ __launch_bounds__(512, 2)
void tgat_post(const float* __restrict__ nf, const unsigned short* __restrict__ ws,
               const unsigned short* __restrict__ qkm, float* __restrict__ out)
{
  __shared__ alignas(16) unsigned short sQb[32 * 136];   // 8.7 KB h_dst bf16
  __shared__ alignas(16) unsigned short sXb[32 * 328];   // 21 KB xhat bf16
  __shared__ float sRed[8][4][4][2];                     // 1 KB
  __shared__ float sStat[32][2];

  const int tid = threadIdx.x, wid = tid >> 6, lane = tid & 63, qd = lane >> 4, lm = lane & 15;
  const int n0 = blockIdx.x * 32;
  const int mt = wid & 1, ws4 = wid >> 1;
  const unsigned short* wvf = ws + WS_WVF;
  const unsigned short* nwc = ws + WS_NWC;
  const float* f32r = (const float*)(ws + WS_F32);

  { // stage h_dst bf16 (coalesced)
    int nn = tid >> 4, k0 = (tid & 15) * 8;
    const float4* src = (const float4*)(nf + (size_t)(n0 + nn) * NODE_IN + k0);
    float4 f0 = src[0], f1 = src[1];
    float v[8] = {f0.x, f0.y, f0.z, f0.w, f1.x, f1.y, f1.z, f1.w};
    *(bf16x8*)&sQb[nn * 136 + k0] = pack8(v);
  }

  // x GEMM: K=2560; wave: 5 N-tiles (nt = ws4 + 4u) for its mtile
  f32x4 acc[5] = {};
  const unsigned short* arow = qkm + (size_t)(n0 + mt * 16 + lm) * 2560;
  for (int kt = 0; kt < 80; ++kt) {
    bf16x8 a = *(const bf16x8*)&arow[kt * 32 + qd * 8];
    #pragma unroll
    for (int u = 0; u < 5; ++u) {
      int c = (ws4 + 4 * u) * 16 + lm;
      bf16x8 b = *(const bf16x8*)&wvf[(size_t)c * 2560 + kt * 32 + qd * 8];
      acc[u] = MFMA16(a, b, acc[u]);
    }
  }

  // epilogue: + cc + residual; LN stats in-register
  float val[5][4];
  float s1[4] = {}, s2[4] = {};
  #pragma unroll
  for (int u = 0; u < 5; ++u) {
    int t = ws4 + 4 * u, c = t * 16 + lm;
    float ccv = f32r[F_CC + c];
    #pragma unroll
    for (int r = 0; r < 4; ++r) {
      float v = acc[u][r] + ccv;
      if (t < 8) v += nf[(size_t)(n0 + mt * 16 + qd * 4 + r) * NODE_IN + c];
      val[u][r] = v;
      s1[r] += v; s2[r] += v * v;
    }
  }
  #pragma unroll
  for (int off = 1; off <= 8; off <<= 1) {
    #pragma unroll
    for (int r = 0; r < 4; ++r) {
      s1[r] += __shfl_xor(s1[r], off);
      s2[r] += __shfl_xor(s2[r], off);
    }
  }
  if (lm == 0) {
    #pragma unroll
    for (int r = 0; r < 4; ++r) { sRed[wid][qd][r][0] = s1[r]; sRed[wid][qd][r][1] = s2[r]; }
  }
  __syncthreads();
  if (tid < 32) {
    int m2 = tid >> 4, rr = tid & 15, q = rr >> 2, r = rr & 3;
    float S = 0.f, S2 = 0.f;
    #pragma unroll
    for (int j = 0; j < 4; ++j) { S += sRed[2 * j + m2][q][r][0]; S2 += sRed[2 * j + m2][q][r][1]; }
    float mean = S * (1.f / D_MODEL);
    float var = S2 * (1.f / D_MODEL) - mean * mean;
    sStat[tid][0] = mean;
    sStat[tid][1] = rsqrtf(var + 1e-5f);
  }
  __syncthreads();
  #pragma unroll
  for (int u = 0; u < 5; ++u) {
    int c = (ws4 + 4 * u) * 16 + lm;
    #pragma unroll
    for (int r = 0; r < 4; ++r) {
      int row = mt * 16 + qd * 4 + r;
      float xh = (val[u][r] - sStat[row][0]) * sStat[row][1];
      sXb[row * 328 + c] = f2bf(xh);
    }
  }
  __syncthreads();

  // out GEMM: M=32, N=128, K=448
  f32x4 oacc[2] = {};
  for (int kt = 0; kt < 14; ++kt) {
    bf16x8 a[2];
    #pragma unroll
    for (int m2 = 0; m2 < 2; ++m2) {
      if (kt < 4) a[m2] = *(const bf16x8*)&sQb[(m2 * 16 + lm) * 136 + kt * 32 + qd * 8];
      else        a[m2] = *(const bf16x8*)&sXb[(m2 * 16 + lm) * 328 + (kt - 4) * 32 + qd * 8];
    }
    int o = wid * 16 + lm;
    bf16x8 b = *(const bf16x8*)&nwc[(size_t)o * IN2 + kt * 32 + qd * 8];
    oacc[0] = MFMA16(a[0], b, oacc[0]);
    oacc[1] = MFMA16(a[1], b, oacc[1]);
  }
  {
    int o = wid * 16 + lm;
    float bz = f32r[F_B2 + o];
    #pragma unroll
    for (int m2 = 0; m2 < 2; ++m2)
      #pragma unroll
      for (int r = 0; r < 4; ++r)
        out[(size_t)(n0 + m2 * 16 + qd * 4 + r) * HID + o] = fmaxf(oacc[m2][r] + bz, 0.f);
  }
}

extern "C" void kernel_launch(void* const* d_in, const int* in_sizes, int n_in,
                              void* d_out, int out_size, void* d_ws, size_t ws_size,
                              hipStream_t stream) {
  const float* nf   = (const float*)d_in[0];
  const float* ef   = (const float*)d_in[1];
  const float* dtp  = (const float*)d_in[2];
  const int*   nidx = (const int*)  d_in[3];
  const float* freq = (const float*)d_in[4];
  const float* ph   = (const float*)d_in[5];
  const float* wq   = (const float*)d_in[6];
  const float* wk   = (const float*)d_in[7];
  const float* wv   = (const float*)d_in[8];
  const float* fcw  = (const float*)d_in[9];
  const float* fcb  = (const float*)d_in[10];
  const float* lng  = (const float*)d_in[11];
  const float* lnb_ = (const float*)d_in[12];
  const float* nw   = (const float*)d_in[13];
  const float* nb   = (const float*)d_in[14];
  float* out = (float*)d_out;
  unsigned short* ws = (unsigned short*)d_ws;
  unsigned short* qkm = ws + WS_QKM;

  prep1<<<228, 256, 0, stream>>>(wq, lng, lnb_, nw, nb, fcb, ph, ws);
  prep2<<<4490, 256, 0, stream>>>(wq, wk, wv, fcw, ws);
  tgat_qk  <<<2560, 256, 0, stream>>>(nf, ws, qkm);
  tgat_attn<<<8192, 256, 0, stream>>>(nf, ef, dtp, nidx, freq, ph, qkm);
  tgat_post<<<256,  512, 0, stream>>>(nf, ws, qkm, out);
}

// Round 7
// 347.919 us; speedup vs baseline: 1.8113x; 1.1041x over previous
//
#include <hip/hip_runtime.h>
#include <math.h>

#define LNB      32
#define NODE_IN  128
#define EDGE_IN  64
#define TIME_D   128
#define D_MODEL  320
#define N_HEAD   8
#define D_K      64
#define NHD      512
#define HID      128
#define IN2      448
#define N_DSTN   8192

typedef __attribute__((ext_vector_type(8))) short bf16x8;
typedef __attribute__((ext_vector_type(4))) float f32x4;
#define MFMA16(a,b,c) __builtin_amdgcn_mfma_f32_16x16x32_bf16(a,b,c,0,0,0)

// ---- ws layout (elements of unsigned short) ----
#define WS_QKM   0            // 8192*2560 : qk (h-major) -> mbar (d*8+h layout), in place
#define WS_WQK   20971520     // 2560*128  : folded wk@wq   (row-major [h*320+d][k])
#define WS_WVF   21299200     // 320*2560  : folded fcw@wv  ([c][d*8+h])
#define WS_NWC   22118400     // 128*448   : [nw1 | nw2*lng]
#define WS_F32   22175744     // 3520 floats
#define WS_X     22182784     // 8192*320 f32 accumulation buffer (atomicAdd)
// total = 27,425,664 shorts = 54.9 MB

#define F_C0     0            // 512
#define F_C0K    512          // 2560
#define F_CC     3072         // 320 : fcb + q-const residual
#define F_B2     3392         // 128 : nb + nw2@lnb

__device__ __forceinline__ unsigned short f2bf(float f) {
  union { float f; unsigned i; } v; v.f = f;
  unsigned x = v.i;
  return (unsigned short)((x + 0x7fffu + ((x >> 16) & 1u)) >> 16); // RTNE
}
__device__ __forceinline__ bf16x8 pack8(const float* v) {
  unsigned short b8[8];
  #pragma unroll
  for (int j = 0; j < 8; ++j) b8[j] = f2bf(v[j]);
  return *(const bf16x8*)b8;
}

// =================== prep1a: elementwise folds ==============================
__global__ __launch_bounds__(256)
void prep1a(const float* __restrict__ nw, const float* __restrict__ lng,
            const float* __restrict__ fcb, const float* __restrict__ ph,
            unsigned short* __restrict__ ws)
{
  int i = blockIdx.x * 256 + threadIdx.x;
  unsigned short* nwc = ws + WS_NWC;
  float* f32r = (float*)(ws + WS_F32);
  if (i < 16384) {                       // nw1 cast
    int o = i >> 7, k = i & 127;
    nwc[o * IN2 + k] = f2bf(nw[(size_t)o * IN2 + k]);
  } else if (i < 57344) {                // nw2g = nw2 * lng
    int j = i - 16384, o = j / 320, c = j - o * 320;
    nwc[o * IN2 + 128 + c] = f2bf(nw[(size_t)o * IN2 + 128 + c] * lng[c]);
  } else if (i < 57664) {                // cc[c] = fcb + q-const
    int c = i - 57344;
    f32r[F_CC + c] = fcb[c] + (c >= 192 ? __cosf(ph[c - 192]) : 0.f);
  }
}

// =================== prep1b: c0 (512 waves) + b2 (128 waves) ===============
__global__ __launch_bounds__(256)
void prep1b(const float* __restrict__ wq, const float* __restrict__ ph,
            const float* __restrict__ nw, const float* __restrict__ lnb_,
            const float* __restrict__ nb, unsigned short* __restrict__ ws)
{
  float* f32r = (float*)(ws + WS_F32);
  int gw = (blockIdx.x * 256 + threadIdx.x) >> 6;
  int ln = threadIdx.x & 63;
  if (gw < 512) {                        // c0[j] = cos(ph) . wq[j][192:]
    float s = __cosf(ph[ln])      * wq[(size_t)gw * D_MODEL + 192 + ln]
            + __cosf(ph[ln + 64]) * wq[(size_t)gw * D_MODEL + 256 + ln];
    #pragma unroll
    for (int off = 32; off >= 1; off >>= 1) s += __shfl_xor(s, off);
    if (ln == 0) f32r[F_C0 + gw] = s;
  } else {                               // b2[o] = nb + nw2 . lnb
    int o = gw - 512;
    float s = 0.f;
    #pragma unroll
    for (int k = 0; k < 5; ++k) {
      int c = ln + 64 * k;
      s += nw[(size_t)o * IN2 + 128 + c] * lnb_[c];
    }
    #pragma unroll
    for (int off = 32; off >= 1; off >>= 1) s += __shfl_xor(s, off);
    if (ln == 0) f32r[F_B2 + o] = nb[o] + s;
  }
}

// =================== prep_c0k: one wave per hd ==============================
__global__ __launch_bounds__(256)
void prep_c0k(const float* __restrict__ wk, unsigned short* __restrict__ ws)
{
  float* f32r = (float*)(ws + WS_F32);
  int gw = (blockIdx.x * 256 + threadIdx.x) >> 6;   // 0..2559
  int ln = threadIdx.x & 63;
  int h = gw / 320, d = gw - h * 320;
  float s = f32r[F_C0 + h * 64 + ln] * wk[(size_t)(h * 64 + ln) * D_MODEL + d];
  #pragma unroll
  for (int off = 32; off >= 1; off >>= 1) s += __shfl_xor(s, off);
  if (ln == 0) f32r[F_C0K + gw] = s;
}

// =================== prep_wqk: LDS-tiled fold (80 blocks) ===================
__global__ __launch_bounds__(256)
void prep_wqk(const float* __restrict__ wq, const float* __restrict__ wk,
              unsigned short* __restrict__ ws)
{
  __shared__ float sQw[64 * 128];
  __shared__ float sKw[64 * 32];
  int h = blockIdx.x / 10, d0 = (blockIdx.x - h * 10) * 32;
  int tid = threadIdx.x;
  #pragma unroll 4
  for (int it = 0; it < 32; ++it) {
    int idx = it * 256 + tid;
    int r = idx >> 7, c = idx & 127;
    sQw[idx] = wq[(size_t)(h * 64 + r) * D_MODEL + c];
  }
  #pragma unroll
  for (int it = 0; it < 8; ++it) {
    int idx = it * 256 + tid;
    int r = idx >> 5, c = idx & 31;
    sKw[idx] = wk[(size_t)(h * 64 + r) * D_MODEL + d0 + c];
  }
  __syncthreads();
  int di = tid >> 3, k0 = (tid & 7) * 16;
  float acc[16] = {};
  for (int dk = 0; dk < 64; ++dk) {
    float w = sKw[dk * 32 + di];
    #pragma unroll
    for (int j = 0; j < 16; ++j) acc[j] += w * sQw[dk * 128 + k0 + j];
  }
  unsigned short* dst = ws + WS_WQK + (size_t)(h * 320 + d0 + di) * 128 + k0;
  #pragma unroll
  for (int j = 0; j < 16; ++j) dst[j] = f2bf(acc[j]);
}

// =================== prep_wvf: LDS-tiled fold (800 blocks) ==================
// wvf[c][d*8+h] = sum_jj fcw[c][h*64+jj] * wv[h*64+jj][d]
__global__ __launch_bounds__(256)
void prep_wvf(const float* __restrict__ fcw, const float* __restrict__ wv,
              unsigned short* __restrict__ ws)
{
  __shared__ float sF[32 * 64];
  __shared__ float sW[64 * 32];
  int b = blockIdx.x;
  int h = b / 100, r2 = b - h * 100;
  int ct = r2 / 10;
  int c0 = ct * 32, d0 = (r2 - ct * 10) * 32;
  int tid = threadIdx.x;
  #pragma unroll
  for (int it = 0; it < 8; ++it) {
    int idx = it * 256 + tid;
    int i = idx >> 6, jj = idx & 63;
    sF[idx] = fcw[(size_t)(c0 + i) * NHD + h * 64 + jj];
  }
  #pragma unroll
  for (int it = 0; it < 8; ++it) {
    int idx = it * 256 + tid;
    int jj = idx >> 5, i = idx & 31;
    sW[idx] = wv[(size_t)(h * 64 + jj) * D_MODEL + d0 + i];
  }
  __syncthreads();
  int ci = tid >> 3, dj0 = (tid & 7) * 4;
  float acc[4] = {};
  for (int jj = 0; jj < 64; ++jj) {
    float f = sF[ci * 64 + jj];
    #pragma unroll
    for (int k = 0; k < 4; ++k) acc[k] += f * sW[jj * 32 + dj0 + k];
  }
  unsigned short* wvf = ws + WS_WVF;
  #pragma unroll
  for (int k = 0; k < 4; ++k)
    wvf[(size_t)(c0 + ci) * 2560 + (size_t)(d0 + dj0 + k) * 8 + h] = f2bf(acc[k]);
}

// =================== K1: qk = nf @ wqk^T + c0k  (h-major layout) ============
__global__ __launch_bounds__(256, 6)
void tgat_qk(const float* __restrict__ nf, const unsigned short* __restrict__ ws,
             unsigned short* __restrict__ qkm)
{
  __shared__ alignas(16) unsigned short sA[64 * 136];
  const int tid = threadIdx.x, wid = tid >> 6, lane = tid & 63, qd = lane >> 4, lm = lane & 15;
  const int mt_blk = blockIdx.x / 20, nt_blk = blockIdx.x - mt_blk * 20;
  const int n0 = mt_blk * 64, c0 = nt_blk * 128;
  const unsigned short* wqk = ws + WS_WQK;
  const float* f32r = (const float*)(ws + WS_F32);

  { // stage A: 64 x 128 bf16 (coalesced)
    int n = tid >> 2, k0 = (tid & 3) * 32;
    const float4* src = (const float4*)(nf + (size_t)(n0 + n) * NODE_IN + k0);
    #pragma unroll
    for (int q = 0; q < 4; ++q) {
      float4 f0 = src[2 * q], f1 = src[2 * q + 1];
      float v[8] = {f0.x, f0.y, f0.z, f0.w, f1.x, f1.y, f1.z, f1.w};
      *(bf16x8*)&sA[n * 136 + k0 + q * 8] = pack8(v);
    }
  }
  __syncthreads();

  f32x4 acc[2][4] = {};
  for (int kt = 0; kt < 4; ++kt) {
    bf16x8 a[4];
    #pragma unroll
    for (int mt = 0; mt < 4; ++mt)
      a[mt] = *(const bf16x8*)&sA[(mt * 16 + lm) * 136 + kt * 32 + qd * 8];
    #pragma unroll
    for (int t = 0; t < 2; ++t) {
      int cg = c0 + (2 * wid + t) * 16 + lm;
      bf16x8 b = *(const bf16x8*)&wqk[(size_t)cg * 128 + kt * 32 + qd * 8];
      #pragma unroll
      for (int mt = 0; mt < 4; ++mt) acc[t][mt] = MFMA16(a[mt], b, acc[t][mt]);
    }
  }
  #pragma unroll
  for (int t = 0; t < 2; ++t) {
    int cg = c0 + (2 * wid + t) * 16 + lm;
    float ck = f32r[F_C0K + cg];
    #pragma unroll
    for (int mt = 0; mt < 4; ++mt)
      #pragma unroll
      for (int r = 0; r < 4; ++r)
        qkm[(size_t)(n0 + mt * 16 + qd * 4 + r) * 2560 + cg] = f2bf(acc[t][mt][r] + ck);
  }
}

// =================== K2: attention (slim LDS, qk prefetch to LDS) ===========
// LDS ~29 KB -> 5 blocks/CU. mbar written in [d*8+h] k-layout.
__global__ __launch_bounds__(256, 5)
void tgat_attn(const float* __restrict__ nf, const float* __restrict__ ef,
               const float* __restrict__ dtp, const int* __restrict__ nidx,
               const float* __restrict__ freq, const float* __restrict__ ph,
               unsigned short* __restrict__ qkm)
{
  __shared__ alignas(16) unsigned short sM[LNB * 328];    // 20.5 KB
  __shared__ alignas(16) unsigned short sQN[8 * 328];     // 5.25 KB
  __shared__ alignas(16) unsigned short sATT[16 * 40];    // 1.28 KB
  __shared__ float sFP[TIME_D], sPH[TIME_D], sDT[LNB];
  __shared__ int   sNI[16];

  const int tid = threadIdx.x;
  const int wid = tid >> 6, lane = tid & 63, qd = lane >> 4, lm = lane & 15;
  const int n = blockIdx.x;
  unsigned short* qn = qkm + (size_t)n * 2560;

  if (tid < TIME_D) { sFP[tid] = freq[tid]; sPH[tid] = ph[tid]; }
  if (tid < 16)  sNI[tid] = nidx[n * 16 + tid];
  if (tid < LNB) sDT[tid] = dtp[(size_t)n * LNB + tid];
  if (tid >= 64 && tid < 192) {          // waves 1-2: qk row -> LDS
    for (int j = tid - 64; j < 320; j += 128) {
      int r = j / 40, c8 = j - r * 40;
      *(bf16x8*)&sQN[r * 328 + c8 * 8] = *(const bf16x8*)&qn[r * 320 + c8 * 8];
    }
  }
  __syncthreads();

  // m build: thread -> (l = g&31, 8 consecutive d)
  #pragma unroll 1
  for (int it = 0; it < 5; ++it) {
    int g = it * 256 + tid;
    int l = g & 31, dg = g >> 5;
    int d0 = dg * 8;
    float v[8];
    if (dg < 16) {
      const float4* src = (const float4*)(nf + (size_t)sNI[l >> 1] * NODE_IN + d0);
      float4 f0 = src[0], f1 = src[1];
      v[0]=f0.x; v[1]=f0.y; v[2]=f0.z; v[3]=f0.w; v[4]=f1.x; v[5]=f1.y; v[6]=f1.z; v[7]=f1.w;
    } else if (dg < 24) {
      const float4* src = (const float4*)(ef + ((size_t)n * LNB + l) * EDGE_IN + (d0 - NODE_IN));
      float4 f0 = src[0], f1 = src[1];
      v[0]=f0.x; v[1]=f0.y; v[2]=f0.z; v[3]=f0.w; v[4]=f1.x; v[5]=f1.y; v[6]=f1.z; v[7]=f1.w;
    } else {
      int dd = d0 - 192;
      float dt = sDT[l];
      #pragma unroll
      for (int j = 0; j < 8; ++j) v[j] = __cosf(dt * sFP[dd + j] + sPH[dd + j]);
    }
    *(bf16x8*)&sM[l * 328 + d0] = pack8(v);
  }
  __syncthreads();

  // scores + softmax (wave 0): D[l][h] = m @ qk^T / 8, qk from LDS
  if (wid == 0) {
    f32x4 acc0 = {}, acc1 = {};
    for (int kt = 0; kt < 10; ++kt) {
      bf16x8 b = {0,0,0,0,0,0,0,0};
      if (lm < 8) b = *(const bf16x8*)&sQN[lm * 328 + kt * 32 + qd * 8];
      bf16x8 a0 = *(const bf16x8*)&sM[lm * 328 + kt * 32 + qd * 8];
      bf16x8 a1 = *(const bf16x8*)&sM[(16 + lm) * 328 + kt * 32 + qd * 8];
      acc0 = MFMA16(a0, b, acc0);
      acc1 = MFMA16(a1, b, acc1);
    }
    float s[8], e[8];
    #pragma unroll
    for (int r = 0; r < 4; ++r) { s[r] = acc0[r] * 0.125f; s[4 + r] = acc1[r] * 0.125f; }
    float mx = s[0];
    #pragma unroll
    for (int i = 1; i < 8; ++i) mx = fmaxf(mx, s[i]);
    mx = fmaxf(mx, __shfl_xor(mx, 16));
    mx = fmaxf(mx, __shfl_xor(mx, 32));
    float sum = 0.f;
    #pragma unroll
    for (int i = 0; i < 8; ++i) { e[i] = __expf(s[i] - mx); sum += e[i]; }
    sum += __shfl_xor(sum, 16);
    sum += __shfl_xor(sum, 32);
    float inv = 1.f / sum;
    #pragma unroll
    for (int i = 0; i < 8; ++i) {
      int l = (i < 4) ? (qd * 4 + i) : (16 + qd * 4 + (i - 4));
      sATT[lm * 40 + l] = f2bf(e[i] * inv);
    }
  }
  __syncthreads();

  // mbar^T: A = m^T (cols of sM), B = attn rows; D[col=h][row=d_local]
  {
    bf16x8 batt = *(const bf16x8*)&sATT[lm * 40 + qd * 8];
    #pragma unroll
    for (int w = 0; w < 5; ++w) {
      int dt = wid * 5 + w;
      int d = dt * 16 + lm;
      unsigned short a8[8];
      #pragma unroll
      for (int j = 0; j < 8; ++j) a8[j] = sM[(qd * 8 + j) * 328 + d];
      f32x4 acc = {};
      acc = MFMA16(*(const bf16x8*)a8, batt, acc);
      if (lm < 8) {
        #pragma unroll
        for (int r = 0; r < 4; ++r)
          qn[(dt * 16 + qd * 4 + r) * 8 + lm] = f2bf(acc[r]);
      }
    }
  }
}

// =================== K3a: x += mbar @ wvf^T (split-K=4, atomics) ============
__global__ __launch_bounds__(512, 4)
void tgat_xgemm(const unsigned short* __restrict__ ws,
                const unsigned short* __restrict__ qkm, float* __restrict__ xacc)
{
  const int tid = threadIdx.x, wid = tid >> 6, lane = tid & 63, qd = lane >> 4, lm = lane & 15;
  const int s = blockIdx.x & 3, mb = blockIdx.x >> 2;
  const int n0 = mb * 32, k0 = s * 640;
  const int mt = wid & 1, ws4 = wid >> 1;
  const unsigned short* wvf = ws + WS_WVF;
  f32x4 acc[5] = {};
  const unsigned short* arow = qkm + (size_t)(n0 + mt * 16 + lm) * 2560 + k0;
  for (int kt = 0; kt < 20; ++kt) {
    bf16x8 a = *(const bf16x8*)&arow[kt * 32 + qd * 8];
    #pragma unroll
    for (int u = 0; u < 5; ++u) {
      int c = (ws4 + 4 * u) * 16 + lm;
      bf16x8 bv = *(const bf16x8*)&wvf[(size_t)c * 2560 + k0 + kt * 32 + qd * 8];
      acc[u] = MFMA16(a, bv, acc[u]);
    }
  }
  #pragma unroll
  for (int u = 0; u < 5; ++u) {
    int c = (ws4 + 4 * u) * 16 + lm;
    #pragma unroll
    for (int r = 0; r < 4; ++r)
      atomicAdd(&xacc[(size_t)(n0 + mt * 16 + qd * 4 + r) * 320 + c], acc[u][r]);
  }
}

// =================== K3b: LN + out GEMM (512 blocks) ========================
__global__ __launch_bounds__(256, 4)
void tgat_post2(const float* __restrict__ nf, const unsigned short* __restrict__ ws,
                const float* __restrict__ xacc, float* __restrict__ out)
{
  __shared__ alignas(16) unsigned short sQb[16 * 136];
  __shared__ alignas(16) unsigned short sXb[16 * 328];
  const int tid = threadIdx.x, wid = tid >> 6, lane = tid & 63, qd = lane >> 4, lm = lane & 15;
  const int n0 = blockIdx.x * 16;
  const unsigned short* nwc = ws + WS_NWC;
  const float* f32r = (const float*)(ws + WS_F32);

  { // stage h_dst bf16
    int nn = tid >> 4, kk = (tid & 15) * 8;
    const float4* src = (const float4*)(nf + (size_t)(n0 + nn) * NODE_IN + kk);
    float4 f0 = src[0], f1 = src[1];
    float v8[8] = {f0.x, f0.y, f0.z, f0.w, f1.x, f1.y, f1.z, f1.w};
    *(bf16x8*)&sQb[nn * 136 + kk] = pack8(v8);
  }
  // LN: thread owns (row rr, cols cl+16u); reduce over the 16-lane row group
  const int rr = tid >> 4, cl = tid & 15;
  float v[20], s1 = 0.f, s2 = 0.f;
  #pragma unroll
  for (int u = 0; u < 20; ++u) {
    int c = u * 16 + cl;
    float x = xacc[(size_t)(n0 + rr) * 320 + c] + f32r[F_CC + c];
    if (c < 128) x += nf[(size_t)(n0 + rr) * NODE_IN + c];
    v[u] = x; s1 += x; s2 += x * x;
  }
  #pragma unroll
  for (int off = 8; off >= 1; off >>= 1) { s1 += __shfl_xor(s1, off); s2 += __shfl_xor(s2, off); }
  float mean = s1 * (1.f / D_MODEL);
  float var  = s2 * (1.f / D_MODEL) - mean * mean;
  float rstd = rsqrtf(var + 1e-5f);
  #pragma unroll
  for (int u = 0; u < 20; ++u) {
    int c = u * 16 + cl;
    sXb[rr * 328 + c] = f2bf((v[u] - mean) * rstd);
  }
  __syncthreads();

  // out GEMM: M=16, N=128, K=448; 4 waves x 2 o-tiles
  #pragma unroll
  for (int t = 0; t < 2; ++t) {
    int o = (wid * 2 + t) * 16 + lm;
    f32x4 acc = {};
    for (int kt = 0; kt < 14; ++kt) {
      bf16x8 a;
      if (kt < 4) a = *(const bf16x8*)&sQb[lm * 136 + kt * 32 + qd * 8];
      else        a = *(const bf16x8*)&sXb[lm * 328 + (kt - 4) * 32 + qd * 8];
      bf16x8 b = *(const bf16x8*)&nwc[(size_t)o * IN2 + kt * 32 + qd * 8];
      acc = MFMA16(a, b, acc);
    }
    float bz = f32r[F_B2 + o];
    #pragma unroll
    for (int r = 0; r < 4; ++r)
      out[(size_t)(n0 + qd * 4 + r) * HID + o] = fmaxf(acc[r] + bz, 0.f);
  }
}

extern "C" void kernel_launch(void* const* d_in, const int* in_sizes, int n_in,
                              void* d_out, int out_size, void* d_ws, size_t ws_size,
                              hipStream_t stream) {
  const float* nf   = (const float*)d_in[0];
  const float* ef   = (const float*)d_in[1];
  const float* dtp  = (const float*)d_in[2];
  const int*   nidx = (const int*)  d_in[3];
  const float* freq = (const float*)d_in[4];
  const float* ph   = (const float*)d_in[5];
  const float* wq   = (const float*)d_in[6];
  const float* wk   = (const float*)d_in[7];
  const float* wv   = (const float*)d_in[8];
  const float* fcw  = (const float*)d_in[9];
  const float* fcb  = (const float*)d_in[10];
  const float* lng  = (const float*)d_in[11];
  const float* lnb_ = (const float*)d_in[12];
  const float* nw   = (const float*)d_in[13];
  const float* nb   = (const float*)d_in[14];
  float* out = (float*)d_out;
  unsigned short* ws = (unsigned short*)d_ws;
  unsigned short* qkm = ws + WS_QKM;
  float* xacc = (float*)(ws + WS_X);

  hipMemsetAsync(xacc, 0, (size_t)N_DSTN * D_MODEL * sizeof(float), stream);
  prep1a  <<<226, 256, 0, stream>>>(nw, lng, fcb, ph, ws);
  prep1b  <<<160, 256, 0, stream>>>(wq, ph, nw, lnb_, nb, ws);
  prep_c0k<<<640, 256, 0, stream>>>(wk, ws);
  prep_wqk<<<80,  256, 0, stream>>>(wq, wk, ws);
  prep_wvf<<<800, 256, 0, stream>>>(fcw, wv, ws);
  tgat_qk   <<<2560, 256, 0, stream>>>(nf, ws, qkm);
  tgat_attn <<<8192, 256, 0, stream>>>(nf, ef, dtp, nidx, freq, ph, qkm);
  tgat_xgemm<<<1024, 512, 0, stream>>>(ws, qkm, xacc);
  tgat_post2<<<512,  256, 0, stream>>>(nf, ws, xacc, out);
}

// Round 8
// 284.524 us; speedup vs baseline: 2.2149x; 1.2228x over previous
//
#include <hip/hip_runtime.h>
#include <math.h>

#define LNB      32
#define NODE_IN  128
#define EDGE_IN  64
#define TIME_D   128
#define D_MODEL  320
#define N_HEAD   8
#define D_K      64
#define NHD      512
#define HID      128
#define IN2      448
#define N_DSTN   8192

typedef __attribute__((ext_vector_type(8))) short bf16x8;
typedef __attribute__((ext_vector_type(4))) float f32x4;
#define MFMA16(a,b,c) __builtin_amdgcn_mfma_f32_16x16x32_bf16(a,b,c,0,0,0)

// ---- ws layout (elements of unsigned short) ----
#define WS_QKM   0            // 8192*2560 : qk (h-major) -> mbar (d*8+h layout), in place
#define WS_WQK   20971520     // 2560*128  : folded wk@wq   (row-major [h*320+d][k])
#define WS_WVF   21299200     // 320*2560  : folded fcw@wv  ([c][d*8+h])
#define WS_NWC   22118400     // 128*448   : [nw1 | nw2*lng]
#define WS_F32   22175744     // 3520 floats
#define WS_X     22182784     // 8192*320 f32 accumulation buffer (atomicAdd)
// total = 27,425,664 shorts = 54.9 MB

#define F_C0     0            // 512
#define F_C0K    512          // 2560
#define F_CC     3072         // 320 : fcb + q-const residual
#define F_B2     3392         // 128 : nb + nw2@lnb

__device__ __forceinline__ unsigned short f2bf(float f) {
  union { float f; unsigned i; } v; v.f = f;
  unsigned x = v.i;
  return (unsigned short)((x + 0x7fffu + ((x >> 16) & 1u)) >> 16); // RTNE
}
__device__ __forceinline__ bf16x8 pack8(const float* v) {
  unsigned short b8[8];
  #pragma unroll
  for (int j = 0; j < 8; ++j) b8[j] = f2bf(v[j]);
  return *(const bf16x8*)b8;
}

// =================== prep1a: elementwise folds ==============================
__global__ __launch_bounds__(256)
void prep1a(const float* __restrict__ nw, const float* __restrict__ lng,
            const float* __restrict__ fcb, const float* __restrict__ ph,
            unsigned short* __restrict__ ws)
{
  int i = blockIdx.x * 256 + threadIdx.x;
  unsigned short* nwc = ws + WS_NWC;
  float* f32r = (float*)(ws + WS_F32);
  if (i < 16384) {                       // nw1 cast
    int o = i >> 7, k = i & 127;
    nwc[o * IN2 + k] = f2bf(nw[(size_t)o * IN2 + k]);
  } else if (i < 57344) {                // nw2g = nw2 * lng
    int j = i - 16384, o = j / 320, c = j - o * 320;
    nwc[o * IN2 + 128 + c] = f2bf(nw[(size_t)o * IN2 + 128 + c] * lng[c]);
  } else if (i < 57664) {                // cc[c] = fcb + q-const
    int c = i - 57344;
    f32r[F_CC + c] = fcb[c] + (c >= 192 ? __cosf(ph[c - 192]) : 0.f);
  }
}

// =================== prep1b: c0 (512 waves) + b2 (128 waves) ===============
__global__ __launch_bounds__(256)
void prep1b(const float* __restrict__ wq, const float* __restrict__ ph,
            const float* __restrict__ nw, const float* __restrict__ lnb_,
            const float* __restrict__ nb, unsigned short* __restrict__ ws)
{
  float* f32r = (float*)(ws + WS_F32);
  int gw = (blockIdx.x * 256 + threadIdx.x) >> 6;
  int ln = threadIdx.x & 63;
  if (gw < 512) {                        // c0[j] = cos(ph) . wq[j][192:]
    float s = __cosf(ph[ln])      * wq[(size_t)gw * D_MODEL + 192 + ln]
            + __cosf(ph[ln + 64]) * wq[(size_t)gw * D_MODEL + 256 + ln];
    #pragma unroll
    for (int off = 32; off >= 1; off >>= 1) s += __shfl_xor(s, off);
    if (ln == 0) f32r[F_C0 + gw] = s;
  } else {                               // b2[o] = nb + nw2 . lnb
    int o = gw - 512;
    float s = 0.f;
    #pragma unroll
    for (int k = 0; k < 5; ++k) {
      int c = ln + 64 * k;
      s += nw[(size_t)o * IN2 + 128 + c] * lnb_[c];
    }
    #pragma unroll
    for (int off = 32; off >= 1; off >>= 1) s += __shfl_xor(s, off);
    if (ln == 0) f32r[F_B2 + o] = nb[o] + s;
  }
}

// =================== prep_c0k: one wave per hd ==============================
__global__ __launch_bounds__(256)
void prep_c0k(const float* __restrict__ wk, unsigned short* __restrict__ ws)
{
  float* f32r = (float*)(ws + WS_F32);
  int gw = (blockIdx.x * 256 + threadIdx.x) >> 6;   // 0..2559
  int ln = threadIdx.x & 63;
  int h = gw / 320, d = gw - h * 320;
  float s = f32r[F_C0 + h * 64 + ln] * wk[(size_t)(h * 64 + ln) * D_MODEL + d];
  #pragma unroll
  for (int off = 32; off >= 1; off >>= 1) s += __shfl_xor(s, off);
  if (ln == 0) f32r[F_C0K + gw] = s;
}

// =================== prep_wqk: LDS-tiled fold (80 blocks) ===================
__global__ __launch_bounds__(256)
void prep_wqk(const float* __restrict__ wq, const float* __restrict__ wk,
              unsigned short* __restrict__ ws)
{
  __shared__ float sQw[64 * 128];
  __shared__ float sKw[64 * 32];
  int h = blockIdx.x / 10, d0 = (blockIdx.x - h * 10) * 32;
  int tid = threadIdx.x;
  #pragma unroll 4
  for (int it = 0; it < 32; ++it) {
    int idx = it * 256 + tid;
    int r = idx >> 7, c = idx & 127;
    sQw[idx] = wq[(size_t)(h * 64 + r) * D_MODEL + c];
  }
  #pragma unroll
  for (int it = 0; it < 8; ++it) {
    int idx = it * 256 + tid;
    int r = idx >> 5, c = idx & 31;
    sKw[idx] = wk[(size_t)(h * 64 + r) * D_MODEL + d0 + c];
  }
  __syncthreads();
  int di = tid >> 3, k0 = (tid & 7) * 16;
  float acc[16] = {};
  for (int dk = 0; dk < 64; ++dk) {
    float w = sKw[dk * 32 + di];
    #pragma unroll
    for (int j = 0; j < 16; ++j) acc[j] += w * sQw[dk * 128 + k0 + j];
  }
  unsigned short* dst = ws + WS_WQK + (size_t)(h * 320 + d0 + di) * 128 + k0;
  #pragma unroll
  for (int j = 0; j < 16; ++j) dst[j] = f2bf(acc[j]);
}

// =================== prep_wvf: LDS-tiled fold (800 blocks) ==================
// wvf[c][d*8+h] = sum_jj fcw[c][h*64+jj] * wv[h*64+jj][d]
__global__ __launch_bounds__(256)
void prep_wvf(const float* __restrict__ fcw, const float* __restrict__ wv,
              unsigned short* __restrict__ ws)
{
  __shared__ float sF[32 * 64];
  __shared__ float sW[64 * 32];
  int b = blockIdx.x;
  int h = b / 100, r2 = b - h * 100;
  int ct = r2 / 10;
  int c0 = ct * 32, d0 = (r2 - ct * 10) * 32;
  int tid = threadIdx.x;
  #pragma unroll
  for (int it = 0; it < 8; ++it) {
    int idx = it * 256 + tid;
    int i = idx >> 6, jj = idx & 63;
    sF[idx] = fcw[(size_t)(c0 + i) * NHD + h * 64 + jj];
  }
  #pragma unroll
  for (int it = 0; it < 8; ++it) {
    int idx = it * 256 + tid;
    int jj = idx >> 5, i = idx & 31;
    sW[idx] = wv[(size_t)(h * 64 + jj) * D_MODEL + d0 + i];
  }
  __syncthreads();
  int ci = tid >> 3, dj0 = (tid & 7) * 4;
  float acc[4] = {};
  for (int jj = 0; jj < 64; ++jj) {
    float f = sF[ci * 64 + jj];
    #pragma unroll
    for (int k = 0; k < 4; ++k) acc[k] += f * sW[jj * 32 + dj0 + k];
  }
  unsigned short* wvf = ws + WS_WVF;
  #pragma unroll
  for (int k = 0; k < 4; ++k)
    wvf[(size_t)(c0 + ci) * 2560 + (size_t)(d0 + dj0 + k) * 8 + h] = f2bf(acc[k]);
}

// =================== K1: qk = nf @ wqk^T + c0k  (h-major layout) ============
__global__ __launch_bounds__(256, 6)
void tgat_qk(const float* __restrict__ nf, const unsigned short* __restrict__ ws,
             unsigned short* __restrict__ qkm)
{
  __shared__ alignas(16) unsigned short sA[64 * 136];
  const int tid = threadIdx.x, wid = tid >> 6, lane = tid & 63, qd = lane >> 4, lm = lane & 15;
  const int mt_blk = blockIdx.x / 20, nt_blk = blockIdx.x - mt_blk * 20;
  const int n0 = mt_blk * 64, c0 = nt_blk * 128;
  const unsigned short* wqk = ws + WS_WQK;
  const float* f32r = (const float*)(ws + WS_F32);

  { // stage A: 64 x 128 bf16 (coalesced)
    int n = tid >> 2, k0 = (tid & 3) * 32;
    const float4* src = (const float4*)(nf + (size_t)(n0 + n) * NODE_IN + k0);
    #pragma unroll
    for (int q = 0; q < 4; ++q) {
      float4 f0 = src[2 * q], f1 = src[2 * q + 1];
      float v[8] = {f0.x, f0.y, f0.z, f0.w, f1.x, f1.y, f1.z, f1.w};
      *(bf16x8*)&sA[n * 136 + k0 + q * 8] = pack8(v);
    }
  }
  __syncthreads();

  f32x4 acc[2][4] = {};
  for (int kt = 0; kt < 4; ++kt) {
    bf16x8 a[4];
    #pragma unroll
    for (int mt = 0; mt < 4; ++mt)
      a[mt] = *(const bf16x8*)&sA[(mt * 16 + lm) * 136 + kt * 32 + qd * 8];
    #pragma unroll
    for (int t = 0; t < 2; ++t) {
      int cg = c0 + (2 * wid + t) * 16 + lm;
      bf16x8 b = *(const bf16x8*)&wqk[(size_t)cg * 128 + kt * 32 + qd * 8];
      #pragma unroll
      for (int mt = 0; mt < 4; ++mt) acc[t][mt] = MFMA16(a[mt], b, acc[t][mt]);
    }
  }
  #pragma unroll
  for (int t = 0; t < 2; ++t) {
    int cg = c0 + (2 * wid + t) * 16 + lm;
    float ck = f32r[F_C0K + cg];
    #pragma unroll
    for (int mt = 0; mt < 4; ++mt)
      #pragma unroll
      for (int r = 0; r < 4; ++r)
        qkm[(size_t)(n0 + mt * 16 + qd * 4 + r) * 2560 + cg] = f2bf(acc[t][mt][r] + ck);
  }
}

// =================== K2: attention (slim LDS, qk prefetch to LDS) ===========
// LDS ~29 KB -> 5 blocks/CU. mbar written in [d*8+h] k-layout.
__global__ __launch_bounds__(256, 5)
void tgat_attn(const float* __restrict__ nf, const float* __restrict__ ef,
               const float* __restrict__ dtp, const int* __restrict__ nidx,
               const float* __restrict__ freq, const float* __restrict__ ph,
               unsigned short* __restrict__ qkm)
{
  __shared__ alignas(16) unsigned short sM[LNB * 328];    // 20.5 KB
  __shared__ alignas(16) unsigned short sQN[8 * 328];     // 5.25 KB
  __shared__ alignas(16) unsigned short sATT[16 * 40];    // 1.28 KB
  __shared__ float sFP[TIME_D], sPH[TIME_D], sDT[LNB];
  __shared__ int   sNI[16];

  const int tid = threadIdx.x;
  const int wid = tid >> 6, lane = tid & 63, qd = lane >> 4, lm = lane & 15;
  const int n = blockIdx.x;
  unsigned short* qn = qkm + (size_t)n * 2560;

  if (tid < TIME_D) { sFP[tid] = freq[tid]; sPH[tid] = ph[tid]; }
  if (tid < 16)  sNI[tid] = nidx[n * 16 + tid];
  if (tid < LNB) sDT[tid] = dtp[(size_t)n * LNB + tid];
  if (tid >= 64 && tid < 192) {          // waves 1-2: qk row -> LDS
    for (int j = tid - 64; j < 320; j += 128) {
      int r = j / 40, c8 = j - r * 40;
      *(bf16x8*)&sQN[r * 328 + c8 * 8] = *(const bf16x8*)&qn[r * 320 + c8 * 8];
    }
  }
  __syncthreads();

  // m build: thread -> (l = g&31, 8 consecutive d)
  #pragma unroll 1
  for (int it = 0; it < 5; ++it) {
    int g = it * 256 + tid;
    int l = g & 31, dg = g >> 5;
    int d0 = dg * 8;
    float v[8];
    if (dg < 16) {
      const float4* src = (const float4*)(nf + (size_t)sNI[l >> 1] * NODE_IN + d0);
      float4 f0 = src[0], f1 = src[1];
      v[0]=f0.x; v[1]=f0.y; v[2]=f0.z; v[3]=f0.w; v[4]=f1.x; v[5]=f1.y; v[6]=f1.z; v[7]=f1.w;
    } else if (dg < 24) {
      const float4* src = (const float4*)(ef + ((size_t)n * LNB + l) * EDGE_IN + (d0 - NODE_IN));
      float4 f0 = src[0], f1 = src[1];
      v[0]=f0.x; v[1]=f0.y; v[2]=f0.z; v[3]=f0.w; v[4]=f1.x; v[5]=f1.y; v[6]=f1.z; v[7]=f1.w;
    } else {
      int dd = d0 - 192;
      float dt = sDT[l];
      #pragma unroll
      for (int j = 0; j < 8; ++j) v[j] = __cosf(dt * sFP[dd + j] + sPH[dd + j]);
    }
    *(bf16x8*)&sM[l * 328 + d0] = pack8(v);
  }
  __syncthreads();

  // scores + softmax (wave 0): D[l][h] = m @ qk^T / 8, qk from LDS
  if (wid == 0) {
    f32x4 acc0 = {}, acc1 = {};
    for (int kt = 0; kt < 10; ++kt) {
      bf16x8 b = {0,0,0,0,0,0,0,0};
      if (lm < 8) b = *(const bf16x8*)&sQN[lm * 328 + kt * 32 + qd * 8];
      bf16x8 a0 = *(const bf16x8*)&sM[lm * 328 + kt * 32 + qd * 8];
      bf16x8 a1 = *(const bf16x8*)&sM[(16 + lm) * 328 + kt * 32 + qd * 8];
      acc0 = MFMA16(a0, b, acc0);
      acc1 = MFMA16(a1, b, acc1);
    }
    float s[8], e[8];
    #pragma unroll
    for (int r = 0; r < 4; ++r) { s[r] = acc0[r] * 0.125f; s[4 + r] = acc1[r] * 0.125f; }
    float mx = s[0];
    #pragma unroll
    for (int i = 1; i < 8; ++i) mx = fmaxf(mx, s[i]);
    mx = fmaxf(mx, __shfl_xor(mx, 16));
    mx = fmaxf(mx, __shfl_xor(mx, 32));
    float sum = 0.f;
    #pragma unroll
    for (int i = 0; i < 8; ++i) { e[i] = __expf(s[i] - mx); sum += e[i]; }
    sum += __shfl_xor(sum, 16);
    sum += __shfl_xor(sum, 32);
    float inv = 1.f / sum;
    #pragma unroll
    for (int i = 0; i < 8; ++i) {
      int l = (i < 4) ? (qd * 4 + i) : (16 + qd * 4 + (i - 4));
      sATT[lm * 40 + l] = f2bf(e[i] * inv);
    }
  }
  __syncthreads();

  // mbar^T: A = m^T (cols of sM), B = attn rows; D[col=h][row=d_local]
  {
    bf16x8 batt = *(const bf16x8*)&sATT[lm * 40 + qd * 8];
    #pragma unroll
    for (int w = 0; w < 5; ++w) {
      int dt = wid * 5 + w;
      int d = dt * 16 + lm;
      unsigned short a8[8];
      #pragma unroll
      for (int j = 0; j < 8; ++j) a8[j] = sM[(qd * 8 + j) * 328 + d];
      f32x4 acc = {};
      acc = MFMA16(*(const bf16x8*)a8, batt, acc);
      if (lm < 8) {
        #pragma unroll
        for (int r = 0; r < 4; ++r)
          qn[(dt * 16 + qd * 4 + r) * 8 + lm] = f2bf(acc[r]);
      }
    }
  }
}

// =================== K3a: x += mbar @ wvf^T (tiled, LDS-A, split-K=4) =======
// M=64/block, 256 thr (4 waves); wave w -> cols [80w,80w+80), all 4 m-tiles.
// A chunk (64x128) staged in LDS once per block; B streamed from L2-hot wvf.
__global__ __launch_bounds__(256)
void tgat_xgemm(const unsigned short* __restrict__ ws,
                const unsigned short* __restrict__ qkm, float* __restrict__ xacc)
{
  __shared__ alignas(16) unsigned short sA[64 * 136];   // 17.4 KB
  const int tid = threadIdx.x, wid = tid >> 6, lane = tid & 63, qd = lane >> 4, lm = lane & 15;
  const int s = blockIdx.x >> 7, mb = blockIdx.x & 127;  // s in high bits: co-dispatched
  const int n0 = mb * 64, k0 = s * 640;                  // blocks share the wvf k-slice
  const unsigned short* wvf = ws + WS_WVF;

  f32x4 acc[4][5] = {};
  for (int kc = 0; kc < 5; ++kc) {
    __syncthreads();
    { // stage A chunk: 64 rows x 128 k (coalesced 64 B/thread)
      int n = tid >> 2, p = (tid & 3) * 32;
      const unsigned short* src = qkm + (size_t)(n0 + n) * 2560 + k0 + kc * 128 + p;
      *(bf16x8*)&sA[n * 136 + p]      = *(const bf16x8*)(src);
      *(bf16x8*)&sA[n * 136 + p + 8]  = *(const bf16x8*)(src + 8);
      *(bf16x8*)&sA[n * 136 + p + 16] = *(const bf16x8*)(src + 16);
      *(bf16x8*)&sA[n * 136 + p + 24] = *(const bf16x8*)(src + 24);
    }
    __syncthreads();
    #pragma unroll
    for (int kt = 0; kt < 4; ++kt) {
      bf16x8 b[5];
      #pragma unroll
      for (int u = 0; u < 5; ++u) {
        int c = wid * 80 + u * 16 + lm;
        b[u] = *(const bf16x8*)&wvf[(size_t)c * 2560 + k0 + kc * 128 + kt * 32 + qd * 8];
      }
      #pragma unroll
      for (int mt = 0; mt < 4; ++mt) {
        bf16x8 a = *(const bf16x8*)&sA[(mt * 16 + lm) * 136 + kt * 32 + qd * 8];
        #pragma unroll
        for (int u = 0; u < 5; ++u) acc[mt][u] = MFMA16(a, b[u], acc[mt][u]);
      }
    }
  }
  #pragma unroll
  for (int mt = 0; mt < 4; ++mt)
    #pragma unroll
    for (int u = 0; u < 5; ++u) {
      int c = wid * 80 + u * 16 + lm;
      #pragma unroll
      for (int r = 0; r < 4; ++r)
        atomicAdd(&xacc[(size_t)(n0 + mt * 16 + qd * 4 + r) * 320 + c], acc[mt][u][r]);
    }
}

// =================== K3b: LN + out GEMM (512 blocks) ========================
__global__ __launch_bounds__(256, 4)
void tgat_post2(const float* __restrict__ nf, const unsigned short* __restrict__ ws,
                const float* __restrict__ xacc, float* __restrict__ out)
{
  __shared__ alignas(16) unsigned short sQb[16 * 136];
  __shared__ alignas(16) unsigned short sXb[16 * 328];
  const int tid = threadIdx.x, wid = tid >> 6, lane = tid & 63, qd = lane >> 4, lm = lane & 15;
  const int n0 = blockIdx.x * 16;
  const unsigned short* nwc = ws + WS_NWC;
  const float* f32r = (const float*)(ws + WS_F32);

  { // stage h_dst bf16
    int nn = tid >> 4, kk = (tid & 15) * 8;
    const float4* src = (const float4*)(nf + (size_t)(n0 + nn) * NODE_IN + kk);
    float4 f0 = src[0], f1 = src[1];
    float v8[8] = {f0.x, f0.y, f0.z, f0.w, f1.x, f1.y, f1.z, f1.w};
    *(bf16x8*)&sQb[nn * 136 + kk] = pack8(v8);
  }
  // LN: thread owns (row rr, cols cl+16u); reduce over the 16-lane row group
  const int rr = tid >> 4, cl = tid & 15;
  float v[20], s1 = 0.f, s2 = 0.f;
  #pragma unroll
  for (int u = 0; u < 20; ++u) {
    int c = u * 16 + cl;
    float x = xacc[(size_t)(n0 + rr) * 320 + c] + f32r[F_CC + c];
    if (c < 128) x += nf[(size_t)(n0 + rr) * NODE_IN + c];
    v[u] = x; s1 += x; s2 += x * x;
  }
  #pragma unroll
  for (int off = 8; off >= 1; off >>= 1) { s1 += __shfl_xor(s1, off); s2 += __shfl_xor(s2, off); }
  float mean = s1 * (1.f / D_MODEL);
  float var  = s2 * (1.f / D_MODEL) - mean * mean;
  float rstd = rsqrtf(var + 1e-5f);
  #pragma unroll
  for (int u = 0; u < 20; ++u) {
    int c = u * 16 + cl;
    sXb[rr * 328 + c] = f2bf((v[u] - mean) * rstd);
  }
  __syncthreads();

  // out GEMM: M=16, N=128, K=448; 4 waves x 2 o-tiles
  #pragma unroll
  for (int t = 0; t < 2; ++t) {
    int o = (wid * 2 + t) * 16 + lm;
    f32x4 acc = {};
    for (int kt = 0; kt < 14; ++kt) {
      bf16x8 a;
      if (kt < 4) a = *(const bf16x8*)&sQb[lm * 136 + kt * 32 + qd * 8];
      else        a = *(const bf16x8*)&sXb[lm * 328 + (kt - 4) * 32 + qd * 8];
      bf16x8 b = *(const bf16x8*)&nwc[(size_t)o * IN2 + kt * 32 + qd * 8];
      acc = MFMA16(a, b, acc);
    }
    float bz = f32r[F_B2 + o];
    #pragma unroll
    for (int r = 0; r < 4; ++r)
      out[(size_t)(n0 + qd * 4 + r) * HID + o] = fmaxf(acc[r] + bz, 0.f);
  }
}

extern "C" void kernel_launch(void* const* d_in, const int* in_sizes, int n_in,
                              void* d_out, int out_size, void* d_ws, size_t ws_size,
                              hipStream_t stream) {
  const float* nf   = (const float*)d_in[0];
  const float* ef   = (const float*)d_in[1];
  const float* dtp  = (const float*)d_in[2];
  const int*   nidx = (const int*)  d_in[3];
  const float* freq = (const float*)d_in[4];
  const float* ph   = (const float*)d_in[5];
  const float* wq   = (const float*)d_in[6];
  const float* wk   = (const float*)d_in[7];
  const float* wv   = (const float*)d_in[8];
  const float* fcw  = (const float*)d_in[9];
  const float* fcb  = (const float*)d_in[10];
  const float* lng  = (const float*)d_in[11];
  const float* lnb_ = (const float*)d_in[12];
  const float* nw   = (const float*)d_in[13];
  const float* nb   = (const float*)d_in[14];
  float* out = (float*)d_out;
  unsigned short* ws = (unsigned short*)d_ws;
  unsigned short* qkm = ws + WS_QKM;
  float* xacc = (float*)(ws + WS_X);

  hipMemsetAsync(xacc, 0, (size_t)N_DSTN * D_MODEL * sizeof(float), stream);
  prep1a  <<<226, 256, 0, stream>>>(nw, lng, fcb, ph, ws);
  prep1b  <<<160, 256, 0, stream>>>(wq, ph, nw, lnb_, nb, ws);
  prep_c0k<<<640, 256, 0, stream>>>(wk, ws);
  prep_wqk<<<80,  256, 0, stream>>>(wq, wk, ws);
  prep_wvf<<<800, 256, 0, stream>>>(fcw, wv, ws);
  tgat_qk   <<<2560, 256, 0, stream>>>(nf, ws, qkm);
  tgat_attn <<<8192, 256, 0, stream>>>(nf, ef, dtp, nidx, freq, ph, qkm);
  tgat_xgemm<<<512,  256, 0, stream>>>(ws, qkm, xacc);
  tgat_post2<<<512,  256, 0, stream>>>(nf, ws, xacc, out);
}